// Round 1
// baseline (591.353 us; speedup 1.0000x reference)
//
#include <hip/hip_runtime.h>

typedef _Float16 f16;
typedef _Float16 f16x8 __attribute__((ext_vector_type(8)));
typedef _Float16 f16x4 __attribute__((ext_vector_type(4)));
typedef _Float16 f16x2 __attribute__((ext_vector_type(2)));
typedef float f32x4 __attribute__((ext_vector_type(4)));

#define MFMA16(a, b, c) __builtin_amdgcn_mfma_f32_16x16x32_f16((a), (b), (c), 0, 0, 0)

constexpr int BATCH = 16384;
constexpr int H     = 256;
constexpr int IN    = 784;
constexpr int OUT   = 10;
constexpr int TSTEP = 50;
constexpr int BM    = 16;    // batch rows per block
constexpr int NTHR  = 512;   // 8 waves; wave w owns h in [32w, 32w+32)
constexpr int SROW  = 264;   // padded f16 row stride for [BM][256] state tiles
constexpr int S0ROW = 40;    // padded f16 row stride for s0 tile (32 cols used, K-padded)
constexpr int DROW  = 800;   // padded f16 row stride for data staging (784 -> 800)

__global__ __launch_bounds__(NTHR, 2) void ep_step_kernel(
    const float* __restrict__ data, const float* __restrict__ s0_in,
    const float* __restrict__ s1_in, const float* __restrict__ s2_in,
    const float* __restrict__ W0, const float* __restrict__ b0,
    const float* __restrict__ W2, const float* __restrict__ b2,
    const float* __restrict__ W4, const float* __restrict__ b4,
    float* __restrict__ out)
{
    __shared__ __align__(16) f16 s1_l[BM * SROW];
    __shared__ __align__(16) f16 s2_l[BM * SROW];
    __shared__ __align__(16) f16 s0_l[BM * S0ROW];
    __shared__ __align__(16) f16 w0n_l[16 * SROW];          // W0 natural, rows padded to 16 with 0
    __shared__ __align__(16) unsigned char xfer_raw[BM * DROW * 2]; // data staging / f32 output transpose

    f16* xferh = (f16*)xfer_raw;

    const int tid  = threadIdx.x;
    const int wave = tid >> 6;
    const int lane = tid & 63;
    const int q    = lane >> 4;   // quad 0..3
    const int l16  = lane & 15;
    const int m0   = blockIdx.x * BM;
    const int h0   = wave * 32;   // this wave's 32-column h slab (2 tiles of 16)

    // ---------------- phase 1: stage data -> f16 LDS, fill W0-natural tile, zero s0 tile -------
    for (int i = tid; i < BM * (DROW / 4); i += NTHR) {
        int m  = i / (DROW / 4);
        int k4 = (i % (DROW / 4)) * 4;
        f16x4 p = {(f16)0.f, (f16)0.f, (f16)0.f, (f16)0.f};
        if (k4 < IN) {  // k4 is a multiple of 4, max in-bounds start is 780 (780+3=783)
            f32x4 v = *(const f32x4*)(data + (size_t)(m0 + m) * IN + k4);
            #pragma unroll
            for (int j = 0; j < 4; ++j) p[j] = (f16)fminf(fmaxf(v[j], 0.f), 1.f); // rho(data)
        }
        *(f16x4*)&xferh[m * DROW + k4] = p;
    }
    for (int i = tid; i < 16 * SROW; i += NTHR) {
        int o = i / SROW, k = i % SROW;
        w0n_l[i] = (o < OUT && k < H) ? (f16)W0[o * H + k] : (f16)0.f;
    }
    for (int i = tid; i < BM * S0ROW; i += NTHR) s0_l[i] = (f16)0.f;
    __syncthreads();

    // ---------------- phase 2: persistent register fragments + x2 precompute -------------------
    // Both main GEMMs computed transposed: C[h][m] so W2 is always the A operand (registers) and
    // state rows are always contiguous B-fragments from LDS.
    f16x8 wB[2][8];  // A'[h][k] = W2[h][k]   (for out1 = s2 @ W2^T)
    f16x8 wA[2][8];  // A'[h][k] = W2[k][h]   (for out2 = s1 @ W2)
    #pragma unroll
    for (int ht = 0; ht < 2; ++ht) {
        int h = h0 + ht * 16 + l16;
        #pragma unroll
        for (int kk = 0; kk < 8; ++kk) {
            int kb = kk * 32 + q * 8;
            f32x4 u0 = *(const f32x4*)(W2 + h * H + kb);
            f32x4 u1 = *(const f32x4*)(W2 + h * H + kb + 4);
            f16x8 wb;
            #pragma unroll
            for (int j = 0; j < 4; ++j) { wb[j] = (f16)u0[j]; wb[j + 4] = (f16)u1[j]; }
            wB[ht][kk] = wb;
            f16x8 wa;
            #pragma unroll
            for (int j = 0; j < 8; ++j) wa[j] = (f16)W2[(kb + j) * H + h];
            wA[ht][kk] = wa;
        }
    }
    // W0 column fragments: A'[h][o] = W0[o][h], K padded 10->32 with zeros
    f16x8 w0c[2];
    #pragma unroll
    for (int ht = 0; ht < 2; ++ht) {
        int h = h0 + ht * 16 + l16;
        #pragma unroll
        for (int j = 0; j < 8; ++j) {
            int o = q * 8 + j;
            w0c[ht][j] = (o < OUT) ? (f16)W0[o * H + h] : (f16)0.f;
        }
    }
    // b2 in C layout
    f32x4 b2r[2];
    #pragma unroll
    for (int ht = 0; ht < 2; ++ht)
        #pragma unroll
        for (int r = 0; r < 4; ++r) b2r[ht][r] = b2[h0 + ht * 16 + q * 4 + r];

    // x2 = rho(data) @ W4^T + b4, computed transposed: C[h][m], kept in registers for all steps
    f32x4 x2a[2] = {{0.f, 0.f, 0.f, 0.f}, {0.f, 0.f, 0.f, 0.f}};
    for (int kk = 0; kk < 25; ++kk) {
        int kb = kk * 32 + q * 8;
        f16x8 bd = *(const f16x8*)&xferh[l16 * DROW + kb];
        #pragma unroll
        for (int ht = 0; ht < 2; ++ht) {
            int h = h0 + ht * 16 + l16;
            f16x8 wa4;
            if (kk < 24) {
                f32x4 u0 = *(const f32x4*)(W4 + (size_t)h * IN + kb);
                f32x4 u1 = *(const f32x4*)(W4 + (size_t)h * IN + kb + 4);
                #pragma unroll
                for (int j = 0; j < 4; ++j) { wa4[j] = (f16)u0[j]; wa4[j + 4] = (f16)u1[j]; }
            } else {
                #pragma unroll
                for (int j = 0; j < 8; ++j) {
                    int k = kb + j;
                    wa4[j] = (k < IN) ? (f16)W4[(size_t)h * IN + k] : (f16)0.f;
                }
            }
            x2a[ht] = MFMA16(wa4, bd, x2a[ht]);
        }
    }
    #pragma unroll
    for (int ht = 0; ht < 2; ++ht)
        #pragma unroll
        for (int r = 0; r < 4; ++r) x2a[ht][r] += b4[h0 + ht * 16 + q * 4 + r];

    // fp32 master states in C layout (row h = q*4+r, col m = l16)
    f32x4 s1m[2], s2m[2];
    #pragma unroll
    for (int ht = 0; ht < 2; ++ht)
        #pragma unroll
        for (int r = 0; r < 4; ++r) {
            int h = h0 + ht * 16 + q * 4 + r;
            s1m[ht][r] = s1_in[(size_t)(m0 + l16) * H + h];
            s2m[ht][r] = s2_in[(size_t)(m0 + l16) * H + h];
        }
    f32x4 s0m = {0.f, 0.f, 0.f, 0.f}, b0r = {0.f, 0.f, 0.f, 0.f};
    if (wave == 0) {
        #pragma unroll
        for (int r = 0; r < 4; ++r) {
            int o = q * 4 + r;
            if (o < OUT) { s0m[r] = s0_in[(size_t)(m0 + l16) * OUT + o]; b0r[r] = b0[o]; }
        }
    }

    // write f16 state copies to LDS (row-major [m][h]); C rows (q*4+r) give h-consecutive pairs
    auto writeback = [&]() {
        #pragma unroll
        for (int ht = 0; ht < 2; ++ht) {
            int hb = h0 + ht * 16 + q * 4;
            f16x2 p;
            p[0] = (f16)s1m[ht][0]; p[1] = (f16)s1m[ht][1];
            *(f16x2*)&s1_l[l16 * SROW + hb] = p;
            p[0] = (f16)s1m[ht][2]; p[1] = (f16)s1m[ht][3];
            *(f16x2*)&s1_l[l16 * SROW + hb + 2] = p;
            p[0] = (f16)s2m[ht][0]; p[1] = (f16)s2m[ht][1];
            *(f16x2*)&s2_l[l16 * SROW + hb] = p;
            p[0] = (f16)s2m[ht][2]; p[1] = (f16)s2m[ht][3];
            *(f16x2*)&s2_l[l16 * SROW + hb + 2] = p;
        }
        if (wave == 0) {
            int ob = q * 4;
            if (ob < OUT) {
                f16x2 p; p[0] = (f16)s0m[0]; p[1] = (f16)s0m[1];
                *(f16x2*)&s0_l[l16 * S0ROW + ob] = p;
                if (ob + 2 < OUT) {
                    f16x2 p2; p2[0] = (f16)s0m[2]; p2[1] = (f16)s0m[3];
                    *(f16x2*)&s0_l[l16 * S0ROW + ob + 2] = p2;
                }
            }
        }
    };
    writeback();
    __syncthreads();

    // ---------------- main loop: T fused steps entirely on-chip --------------------------------
    for (int t = 0; t < TSTEP; ++t) {
        f32x4 o1[2] = {{0.f,0.f,0.f,0.f},{0.f,0.f,0.f,0.f}};  // (s2 @ W2^T + s0 @ W0)^T
        f32x4 o2[2] = {{0.f,0.f,0.f,0.f},{0.f,0.f,0.f,0.f}};  // (s1 @ W2)^T
        f32x4 o0    = {0.f,0.f,0.f,0.f};                      // (s1 @ W0^T)^T  (wave 0 only)
        #pragma unroll
        for (int kk = 0; kk < 8; ++kk) {
            int kb = kk * 32 + q * 8;
            f16x8 bs1 = *(const f16x8*)&s1_l[l16 * SROW + kb];
            f16x8 bs2 = *(const f16x8*)&s2_l[l16 * SROW + kb];
            o2[0] = MFMA16(wA[0][kk], bs1, o2[0]);
            o2[1] = MFMA16(wA[1][kk], bs1, o2[1]);
            o1[0] = MFMA16(wB[0][kk], bs2, o1[0]);
            o1[1] = MFMA16(wB[1][kk], bs2, o1[1]);
            if (wave == 0) {
                f16x8 a0 = *(const f16x8*)&w0n_l[l16 * SROW + kb];
                o0 = MFMA16(a0, bs1, o0);
            }
        }
        {   // + s0 @ W0 contribution into o1 (K padded to 32)
            f16x8 bs0 = *(const f16x8*)&s0_l[l16 * S0ROW + q * 8];
            o1[0] = MFMA16(w0c[0], bs0, o1[0]);
            o1[1] = MFMA16(w0c[1], bs0, o1[1]);
        }
        __syncthreads();  // all reads of old state done
        #pragma unroll
        for (int ht = 0; ht < 2; ++ht)
            #pragma unroll
            for (int r = 0; r < 4; ++r) {
                float n1 = 0.5f * s1m[ht][r] + 0.5f * (o1[ht][r] + b2r[ht][r]);
                s1m[ht][r] = fminf(fmaxf(n1, 0.f), 1.f);
                float n2 = 0.5f * s2m[ht][r] + 0.5f * (o2[ht][r] + x2a[ht][r]);
                s2m[ht][r] = fminf(fmaxf(n2, 0.f), 1.f);
            }
        if (wave == 0) {
            #pragma unroll
            for (int r = 0; r < 4; ++r) {
                float n0 = 0.5f * s0m[r] + 0.5f * (o0[r] + b0r[r]);
                s0m[r] = fminf(fmaxf(n0, 0.f), 1.f);
            }
        }
        writeback();
        __syncthreads();  // new state visible to all waves
    }

    // ---------------- epilogue: coalesced output via LDS transpose -----------------------------
    if (wave == 0) {
        #pragma unroll
        for (int r = 0; r < 4; ++r) {
            int o = q * 4 + r;
            if (o < OUT) out[(size_t)(m0 + l16) * OUT + o] = s0m[r];
        }
    }
    float* xf = (float*)xfer_raw;
    float* o1p = out + (size_t)BATCH * OUT;
    float* o2p = o1p + (size_t)BATCH * H;
    #pragma unroll
    for (int ht = 0; ht < 2; ++ht)
        #pragma unroll
        for (int r = 0; r < 4; ++r) xf[l16 * H + h0 + ht * 16 + q * 4 + r] = s1m[ht][r];
    __syncthreads();
    for (int i = tid; i < BM * H / 4; i += NTHR) {
        int m = i >> 6, c = (i & 63) * 4;
        f32x4 v = *(const f32x4*)&xf[m * H + c];
        *(f32x4*)&o1p[(size_t)(m0 + m) * H + c] = v;
    }
    __syncthreads();
    #pragma unroll
    for (int ht = 0; ht < 2; ++ht)
        #pragma unroll
        for (int r = 0; r < 4; ++r) xf[l16 * H + h0 + ht * 16 + q * 4 + r] = s2m[ht][r];
    __syncthreads();
    for (int i = tid; i < BM * H / 4; i += NTHR) {
        int m = i >> 6, c = (i & 63) * 4;
        f32x4 v = *(const f32x4*)&xf[m * H + c];
        *(f32x4*)&o2p[(size_t)(m0 + m) * H + c] = v;
    }
}

extern "C" void kernel_launch(void* const* d_in, const int* in_sizes, int n_in,
                              void* d_out, int out_size, void* d_ws, size_t ws_size,
                              hipStream_t stream) {
    const float* data  = (const float*)d_in[0];
    const float* s0_in = (const float*)d_in[1];
    const float* s1_in = (const float*)d_in[2];
    const float* s2_in = (const float*)d_in[3];
    const float* W0    = (const float*)d_in[4];
    const float* b0    = (const float*)d_in[5];
    const float* W2    = (const float*)d_in[6];
    const float* b2    = (const float*)d_in[7];
    const float* W4    = (const float*)d_in[8];
    const float* b4    = (const float*)d_in[9];
    float* out = (float*)d_out;

    ep_step_kernel<<<BATCH / BM, NTHR, 0, stream>>>(
        data, s0_in, s1_in, s2_in, W0, b0, W2, b2, W4, b4, out);
}